// Round 5
// baseline (430.074 us; speedup 1.0000x reference)
//
#include <hip/hip_runtime.h>
#include <hip/hip_bf16.h>

#define B_      64
#define S_      4096
#define DIM_    256
#define DA_     64
#define NEG_    (-1e30f)
#define CHUNKS_ 16
#define ROWS_   256           // seq rows per chunk (4 tiles x 64)
#define LDH_    264           // halves per LDS row (256 + 8 pad)
#define PSTR_   260           // partial stride: m, l, pad, pad, o[256]

typedef _Float16 half8 __attribute__((ext_vector_type(8)));
typedef float float4v __attribute__((ext_vector_type(4)));

// tanh(x) = 1 - 2/(exp(2x)+1); exact at +/-inf; err ~1e-6 << 2e-3 tol.
__device__ __forceinline__ float tanh_fast(float x) {
    float e = __expf(2.0f * x);
    return 1.0f - 2.0f * __builtin_amdgcn_rcpf(e + 1.0f);
}

// Kernel 0 (unchanged): A (DIM x DA fp32) -> fp16 swizzled into MFMA A-fragment
// order; detect mask encoding (flag=1 => int32 elements, flag=0 => 1-byte).
// at_sw index: ((nt*8+kb)*64 + lane)*8 + j = a[d][n],
//   d = kb*32 + (lane>>4)*8 + j, n = nt*16 + (lane&15)
__global__ __launch_bounds__(256) void prep_kernel(
    const float* __restrict__ a, const void* __restrict__ mask,
    _Float16* __restrict__ at_sw, int* __restrict__ flag)
{
    int idx = blockIdx.x * 256 + threadIdx.x;   // 0..16383
    int j    = idx & 7;
    int lane = (idx >> 3) & 63;
    int kbnt = idx >> 9;
    int kb   = kbnt & 7;
    int nt   = kbnt >> 3;
    int d  = kb * 32 + (lane >> 4) * 8 + j;
    int kf = nt * 16 + (lane & 15);
    at_sw[idx] = (_Float16)a[d * DA_ + kf];

    if (blockIdx.x == 0) {
        __shared__ int anynz;
        if (threadIdx.x == 0) anynz = 0;
        __syncthreads();
        const unsigned char* mb = (const unsigned char*)mask;
        int base = threadIdx.x * 4;   // scan first 1024 bytes
        int v = mb[base + 1] | mb[base + 2] | mb[base + 3];
        if (v) atomicOr(&anynz, 1);
        __syncthreads();
        if (threadIdx.x == 0) *flag = (anynz == 0) ? 1 : 0;
    }
}

// R9 fused kernel: R6's wave-private barrier-free structure, two fixes:
//  (1) fp16 tile buffer (33.8 KiB) + asw (32 KiB) = 66.5 KiB LDS
//      -> 2 blocks/CU, 2 waves/SIMD (R6's 133 KiB fp32 dbuf forced 1/SIMD,
//      every latency exposed -> 2.1 TB/s).
//  (2) T14 reg-split staging: issue next tile's 16 coalesced 1-KiB-row loads
//      into pf[16] BEFORE compute, cvt+ds_write AFTER accumulate. HBM latency
//      hides under ~1500 cyc of compute; MFMA now reads fp16 LDS directly
//      (1 ds_read_b128/kb, no cvt chain on the critical path).
// Kept from R6/R7: wave owns rows wave*16..+15 (zero main-loop barriers,
// single-buffer LDS is safe: same-wave ds ordering via compiler lgkmcnt),
// per-wave online softmax + per-wave partials, mask prefetch, per-thread
// acc0..3 (R5/R7 lesson: o[64]/per-lane-row accumulators always spill).
__global__ __launch_bounds__(256, 2) void fused_kernel(
    const float* __restrict__ h, const _Float16* __restrict__ at_sw,
    const float* __restrict__ bvec, const void* __restrict__ mask,
    const int* __restrict__ flag, float* __restrict__ part)
{
    __shared__ _Float16 asw[16384];      // 32 KiB a-fragments
    __shared__ _Float16 hf[64 * LDH_];   // 33,792 B; wave-private 16-row slices

    const int t    = threadIdx.x;
    const int wave = t >> 6;
    const int lane = t & 63;
    const int quad = lane >> 4;
    const int nrow = lane & 15;
    const bool int32enc = (*flag != 0);

    {   // stage a-fragments (L2-hot from prep)
        const uint4* g = (const uint4*)at_sw;
        uint4* l = (uint4*)asw;
        #pragma unroll
        for (int i = 0; i < 8; ++i) l[i * 256 + t] = g[i * 256 + t];
    }

    float4 bq[4];
    #pragma unroll
    for (int nt = 0; nt < 4; ++nt)
        bq[nt] = *(const float4*)(bvec + nt * 16 + quad * 4);

    const int cg = blockIdx.x;           // chunk id, 0..1023
    const int b  = cg >> 4;
    const int c  = cg & 15;
    const long long crow = (long long)b * S_ + c * ROWS_;
    const long long row0 = crow + wave * 16 + nrow;   // this lane's tile-0 row

    // prefetch all 4 tile masks up front (no per-tile mask stall)
    int mv0, mv1, mv2, mv3;
    if (int32enc) {
        const int* mi = (const int*)mask + row0;
        mv0 = mi[0]; mv1 = mi[64]; mv2 = mi[128]; mv3 = mi[192];
    } else {
        const unsigned char* mb = (const unsigned char*)mask + row0;
        mv0 = mb[0]; mv1 = mb[64]; mv2 = mb[128]; mv3 = mb[192];
    }

    __syncthreads();                     // asw visible (only barrier)

    const float* wbase = h + (crow + wave * 16) * DIM_;   // wave's row slice
    float acc0 = 0.f, acc1 = 0.f, acc2 = 0.f, acc3 = 0.f;
    float m_w = NEG_, l_w = 0.f;

    float4 pf[16];                       // in-flight staging regs (static idx)

    // prologue: load + write tile 0 (cold-start vmcnt wait, once)
    #pragma unroll
    for (int i = 0; i < 16; ++i)
        pf[i] = *(const float4*)(wbase + (size_t)i * DIM_ + lane * 4);
    #pragma unroll
    for (int i = 0; i < 16; ++i) {
        union { _Float16 hh[4]; unsigned long long u; } pk;
        pk.hh[0] = (_Float16)pf[i].x; pk.hh[1] = (_Float16)pf[i].y;
        pk.hh[2] = (_Float16)pf[i].z; pk.hh[3] = (_Float16)pf[i].w;
        *(unsigned long long*)&hf[(wave * 16 + i) * LDH_ + lane * 4] = pk.u;
    }

    auto body = [&](int tile, int mv) {
        // ---- T14 issue-early: next tile's rows -> pf (coalesced 1 KiB/instr)
        if (tile < 3) {
            const float* nb = wbase + (size_t)(tile + 1) * 64 * DIM_;
            #pragma unroll
            for (int i = 0; i < 16; ++i)
                pf[i] = *(const float4*)(nb + (size_t)i * DIM_ + lane * 4);
        }

        // ---- MFMA: z^T[n][own row]; B-fragment = own row's fp16 from LDS ----
        const _Float16* hrow_l = &hf[(wave * 16 + nrow) * LDH_];
        float4v accm[4];
        #pragma unroll
        for (int nt = 0; nt < 4; ++nt) accm[nt] = (float4v){0.f, 0.f, 0.f, 0.f};
        #pragma unroll
        for (int kb = 0; kb < 8; ++kb) {
            half8 bf = *(const half8*)(hrow_l + kb * 32 + quad * 8);
            #pragma unroll
            for (int nt = 0; nt < 4; ++nt) {
                half8 af = *(const half8*)&asw[((nt * 8 + kb) * 64 + lane) * 8];
                accm[nt] = __builtin_amdgcn_mfma_f32_16x16x32_f16(af, bf, accm[nt], 0, 0, 0);
            }
        }

        // ---- e[own row]: lane holds n = nt*16 + quad*4 + r; reduce quads ----
        float p = 0.f;
        #pragma unroll
        for (int nt = 0; nt < 4; ++nt) {
            p += tanh_fast(accm[nt][0]) * bq[nt].x;
            p += tanh_fast(accm[nt][1]) * bq[nt].y;
            p += tanh_fast(accm[nt][2]) * bq[nt].z;
            p += tanh_fast(accm[nt][3]) * bq[nt].w;
        }
        p += __shfl_xor(p, 16);
        p += __shfl_xor(p, 32);          // uniform across quads

        // ---- per-wave online softmax over its 16 rows ----
        float ev = mv ? NEG_ : p;
        float mx = ev;
        mx = fmaxf(mx, __shfl_xor(mx, 1));
        mx = fmaxf(mx, __shfl_xor(mx, 2));
        mx = fmaxf(mx, __shfl_xor(mx, 4));
        mx = fmaxf(mx, __shfl_xor(mx, 8));
        float m_new = fmaxf(m_w, mx);
        float rs  = __expf(m_w - m_new);     // first tile: exp(-1e30) = 0
        float w_s = __expf(ev - m_new);
        float sm = w_s;
        sm += __shfl_xor(sm, 1);
        sm += __shfl_xor(sm, 2);
        sm += __shfl_xor(sm, 4);
        sm += __shfl_xor(sm, 8);
        l_w = l_w * rs + sm;
        m_w = m_new;
        acc0 *= rs; acc1 *= rs; acc2 *= rs; acc3 *= rs;

        // ---- accumulate own 4 dims over the wave's 16 rows (fp16 LDS) ----
        #pragma unroll
        for (int s = 0; s < 16; ++s) {
            float wv = __shfl(w_s, s);       // row wave*16+s's weight
            union { ushort4 u; _Float16 hh[4]; } pk;
            pk.u = *(const ushort4*)((const unsigned short*)
                       &hf[(wave * 16 + s) * LDH_ + lane * 4]);
            acc0 = fmaf(wv, (float)pk.hh[0], acc0);
            acc1 = fmaf(wv, (float)pk.hh[1], acc1);
            acc2 = fmaf(wv, (float)pk.hh[2], acc2);
            acc3 = fmaf(wv, (float)pk.hh[3], acc3);
        }

        // ---- T14 write-late: cvt + ds_write next tile (pf mostly landed) ----
        if (tile < 3) {
            #pragma unroll
            for (int i = 0; i < 16; ++i) {
                union { _Float16 hh[4]; unsigned long long u; } pk;
                pk.hh[0] = (_Float16)pf[i].x; pk.hh[1] = (_Float16)pf[i].y;
                pk.hh[2] = (_Float16)pf[i].z; pk.hh[3] = (_Float16)pf[i].w;
                *(unsigned long long*)&hf[(wave * 16 + i) * LDH_ + lane * 4] = pk.u;
            }
        }
    };
    body(0, mv0); body(1, mv1); body(2, mv2); body(3, mv3);

    // ---- per-wave partial: acc IS the wave's o for dims lane*4..+3 ----
    float* pc = part + (size_t)(cg * 4 + wave) * PSTR_;
    *(float4*)(pc + 4 + lane * 4) = make_float4(acc0, acc1, acc2, acc3);
    if (lane == 0) { pc[0] = m_w; pc[1] = l_w; }
}

// Kernel 2: merge 64 per-wave partials (16 chunks x 4 waves) -> out[b][d]
__global__ __launch_bounds__(256) void merge_kernel(
    const float* __restrict__ part, float* __restrict__ out)
{
    const int b = blockIdx.x;
    const int t = threadIdx.x;
    const float* pb = part + (size_t)b * 64 * PSTR_;
    float M = NEG_;
    #pragma unroll
    for (int i = 0; i < 64; ++i) M = fmaxf(M, pb[i * PSTR_]);
    float L = 0.f, o = 0.f;
    #pragma unroll
    for (int i = 0; i < 64; ++i) {
        float sc = __expf(pb[i * PSTR_] - M);
        L += pb[i * PSTR_ + 1] * sc;
        o += pb[i * PSTR_ + 4 + t] * sc;
    }
    out[b * DIM_ + t] = o / L;
}

extern "C" void kernel_launch(void* const* d_in, const int* in_sizes, int n_in,
                              void* d_out, int out_size, void* d_ws, size_t ws_size,
                              hipStream_t stream) {
    const float* h    = (const float*)d_in[0];
    const void*  mask = d_in[1];
    const float* a    = (const float*)d_in[2];
    const float* bvec = (const float*)d_in[3];
    float* out = (float*)d_out;

    char* ws = (char*)d_ws;
    _Float16* at_sw = (_Float16*)ws;              // 32,768 B
    int* flag       = (int*)(ws + 32768);
    float* part     = (float*)(ws + 36864);       // 4096 * 260 * 4 B ~= 4.3 MiB

    prep_kernel<<<64, 256, 0, stream>>>(a, mask, at_sw, flag);
    fused_kernel<<<B_ * CHUNKS_, 256, 0, stream>>>(h, at_sw, bvec, mask, flag, part);
    merge_kernel<<<B_, 256, 0, stream>>>(part, out);
}

// Round 6
// 418.922 us; speedup vs baseline: 1.0266x; 1.0266x over previous
//
#include <hip/hip_runtime.h>
#include <hip/hip_bf16.h>

#define B_      64
#define S_      4096
#define DIM_    256
#define DA_     64
#define NEG_    (-1e30f)
#define NTILE_  64            // 64-row tiles per batch (S/64)
#define LDH_    264           // halves per LDS row (256 + 8 pad)
#define PSTR_   264           // partial stride: m, l, pad, pad, o[256], pad4 (1056 B, 16B-aligned)

typedef _Float16 half8 __attribute__((ext_vector_type(8)));
typedef float float4v __attribute__((ext_vector_type(4)));

// tanh(x) = 1 - 2/(exp(2x)+1); exact at +/-inf; err ~1e-6 << 2e-3 tol.
__device__ __forceinline__ float tanh_fast(float x) {
    float e = __expf(2.0f * x);
    return 1.0f - 2.0f * __builtin_amdgcn_rcpf(e + 1.0f);
}

// Kernel 0 (unchanged): A (DIM x DA fp32) -> fp16 swizzled into MFMA A-fragment
// order; detect mask encoding (flag=1 => int32 elements, flag=0 => 1-byte).
// at_sw index: ((nt*8+kb)*64 + lane)*8 + j = a[d][n],
//   d = kb*32 + (lane>>4)*8 + j, n = nt*16 + (lane&15)
__global__ __launch_bounds__(256) void prep_kernel(
    const float* __restrict__ a, const void* __restrict__ mask,
    _Float16* __restrict__ at_sw, int* __restrict__ flag)
{
    int idx = blockIdx.x * 256 + threadIdx.x;   // 0..16383
    int j    = idx & 7;
    int lane = (idx >> 3) & 63;
    int kbnt = idx >> 9;
    int kb   = kbnt & 7;
    int nt   = kbnt >> 3;
    int d  = kb * 32 + (lane >> 4) * 8 + j;
    int kf = nt * 16 + (lane & 15);
    at_sw[idx] = (_Float16)a[d * DA_ + kf];

    if (blockIdx.x == 0) {
        __shared__ int anynz;
        if (threadIdx.x == 0) anynz = 0;
        __syncthreads();
        const unsigned char* mb = (const unsigned char*)mask;
        int base = threadIdx.x * 4;   // scan first 1024 bytes
        int v = mb[base + 1] | mb[base + 2] | mb[base + 3];
        if (v) atomicOr(&anynz, 1);
        __syncthreads();
        if (threadIdx.x == 0) *flag = (anynz == 0) ? 1 : 0;
    }
}

// R10 fused kernel: single-tile blocks, spill-proof, barrier-free main body.
// Spill rule from R5/R7/R9 (VGPR=84/128/128, scratch WRITE 122/301/160 MB):
// any >=16-reg array live across the MFMA section spills. Here the only
// arrays are hv[8] (consumed within a half-phase) and accm[4]; peak live
// ~95 VGPR. h fragments load straight from global (lane-row-aligned, full
// 128B-line use), are cvt'd once, feed MFMA from registers AND are written
// through to fp16 LDS for the accumulate phase (per-thread acc0..3 only).
// Grid = 4096 single-tile blocks: no cross-tile loop, no online-softmax
// carry, per-(tile,wave) partials, zero barriers after the asw prologue.
// LDS 66.5 KB -> 2 blocks/CU (8 waves/CU), 2x R6's TLP.
__global__ __launch_bounds__(256, 2) void fused_kernel(
    const float* __restrict__ h, const _Float16* __restrict__ at_sw,
    const float* __restrict__ bvec, const void* __restrict__ mask,
    const int* __restrict__ flag, float* __restrict__ part)
{
    __shared__ _Float16 asw[16384];      // 32 KiB a-fragments
    __shared__ _Float16 hf[64 * LDH_];   // 33,792 B; wave-private 16-row slices

    const int t    = threadIdx.x;
    const int wave = t >> 6;
    const int lane = t & 63;
    const int quad = lane >> 4;
    const int nrow = lane & 15;
    const bool int32enc = (*flag != 0);

    {   // stage a-fragments (L2-hot from prep)
        const uint4* g = (const uint4*)at_sw;
        uint4* l = (uint4*)asw;
        #pragma unroll
        for (int i = 0; i < 8; ++i) l[i * 256 + t] = g[i * 256 + t];
    }

    float4 bq[4];
    #pragma unroll
    for (int nt = 0; nt < 4; ++nt)
        bq[nt] = *(const float4*)(bvec + nt * 16 + quad * 4);

    const int bid = blockIdx.x;          // (b, t16): b = bid>>6, tile = bid&63
    const long long rowg = ((long long)(bid >> 6) * S_) + (bid & 63) * 64
                         + wave * 16 + nrow;        // this lane's row
    const float* hp = h + rowg * DIM_ + quad * 8;   // own row, own quad offset

    // own-row mask (uniform across quads: address has no quad term)
    int mv = int32enc ? ((const int*)mask)[rowg]
                      : (int)((const unsigned char*)mask)[rowg];

    __syncthreads();                     // asw visible (only barrier)

    const int lrow = wave * 16 + nrow;   // own LDS row
    float4v accm[4];
    #pragma unroll
    for (int nt = 0; nt < 4; ++nt) accm[nt] = (float4v){0.f, 0.f, 0.f, 0.f};

    // two half-phases: 8 independent float4 loads, then cvt + LDS write-through
    // + MFMA (hv live range stays inside the half-phase -> no spill)
    #pragma unroll
    for (int kh = 0; kh < 2; ++kh) {
        float4 hv[8];
        #pragma unroll
        for (int i = 0; i < 8; ++i) {
            int kb = kh * 4 + (i >> 1);
            hv[i] = *(const float4*)(hp + kb * 32 + (i & 1) * 4);
        }
        #pragma unroll
        for (int k = 0; k < 4; ++k) {
            int kb = kh * 4 + k;
            union { _Float16 hh[8]; half8 v; } pk;
            pk.hh[0] = (_Float16)hv[2 * k].x;     pk.hh[1] = (_Float16)hv[2 * k].y;
            pk.hh[2] = (_Float16)hv[2 * k].z;     pk.hh[3] = (_Float16)hv[2 * k].w;
            pk.hh[4] = (_Float16)hv[2 * k + 1].x; pk.hh[5] = (_Float16)hv[2 * k + 1].y;
            pk.hh[6] = (_Float16)hv[2 * k + 1].z; pk.hh[7] = (_Float16)hv[2 * k + 1].w;
            // write-through for the accumulate phase (own row slice)
            *(half8*)&hf[lrow * LDH_ + kb * 32 + quad * 8] = pk.v;
            #pragma unroll
            for (int nt = 0; nt < 4; ++nt) {
                half8 af = *(const half8*)&asw[((nt * 8 + kb) * 64 + lane) * 8];
                accm[nt] = __builtin_amdgcn_mfma_f32_16x16x32_f16(af, pk.v, accm[nt], 0, 0, 0);
            }
        }
    }

    // e[own row]: lane holds n = nt*16 + quad*4 + r; reduce over quads
    float p = 0.f;
    #pragma unroll
    for (int nt = 0; nt < 4; ++nt) {
        p += tanh_fast(accm[nt][0]) * bq[nt].x;
        p += tanh_fast(accm[nt][1]) * bq[nt].y;
        p += tanh_fast(accm[nt][2]) * bq[nt].z;
        p += tanh_fast(accm[nt][3]) * bq[nt].w;
    }
    p += __shfl_xor(p, 16);
    p += __shfl_xor(p, 32);              // uniform across quads

    // per-wave single-tile softmax over its 16 rows (no online carry)
    float ev = mv ? NEG_ : p;
    float mx = ev;
    mx = fmaxf(mx, __shfl_xor(mx, 1));
    mx = fmaxf(mx, __shfl_xor(mx, 2));
    mx = fmaxf(mx, __shfl_xor(mx, 4));
    mx = fmaxf(mx, __shfl_xor(mx, 8));
    float w_s = __expf(ev - mx);         // all-masked tile: w=1, zeroed at merge
    float sm = w_s;
    sm += __shfl_xor(sm, 1);
    sm += __shfl_xor(sm, 2);
    sm += __shfl_xor(sm, 4);
    sm += __shfl_xor(sm, 8);

    // accumulate own 4 dims over the wave's 16 rows (fp16 LDS, written above)
    float acc0 = 0.f, acc1 = 0.f, acc2 = 0.f, acc3 = 0.f;
    #pragma unroll
    for (int s = 0; s < 16; ++s) {
        float wv = __shfl(w_s, s);       // row wave*16+s's weight (v_readlane)
        union { ushort4 u; _Float16 hh[4]; } pk;
        pk.u = *(const ushort4*)((const unsigned short*)
                   &hf[(wave * 16 + s) * LDH_ + lane * 4]);
        acc0 = fmaf(wv, (float)pk.hh[0], acc0);
        acc1 = fmaf(wv, (float)pk.hh[1], acc1);
        acc2 = fmaf(wv, (float)pk.hh[2], acc2);
        acc3 = fmaf(wv, (float)pk.hh[3], acc3);
    }

    // per-(tile,wave) partial
    float* pc = part + (size_t)(bid * 4 + wave) * PSTR_;
    *(float4*)(pc + 4 + lane * 4) = make_float4(acc0, acc1, acc2, acc3);
    if (lane == 0) { pc[0] = mx; pc[1] = sm; }
}

// Kernel 2: merge 256 per-(tile,wave) partials per batch -> out[b][d]
__global__ __launch_bounds__(256) void merge_kernel(
    const float* __restrict__ part, float* __restrict__ out)
{
    const int b = blockIdx.x;
    const int t = threadIdx.x;
    const float* pb = part + (size_t)b * 256 * PSTR_;
    float M = NEG_;
    #pragma unroll 8
    for (int i = 0; i < 256; ++i) M = fmaxf(M, pb[i * PSTR_]);
    float L = 0.f, o = 0.f;
    #pragma unroll 8
    for (int i = 0; i < 256; ++i) {
        float sc = __expf(pb[i * PSTR_] - M);
        L += pb[i * PSTR_ + 1] * sc;
        o += pb[i * PSTR_ + 4 + t] * sc;
    }
    out[b * DIM_ + t] = o / L;
}

extern "C" void kernel_launch(void* const* d_in, const int* in_sizes, int n_in,
                              void* d_out, int out_size, void* d_ws, size_t ws_size,
                              hipStream_t stream) {
    const float* h    = (const float*)d_in[0];
    const void*  mask = d_in[1];
    const float* a    = (const float*)d_in[2];
    const float* bvec = (const float*)d_in[3];
    float* out = (float*)d_out;

    char* ws = (char*)d_ws;
    _Float16* at_sw = (_Float16*)ws;              // 32,768 B
    int* flag       = (int*)(ws + 32768);
    float* part     = (float*)(ws + 36864);       // 16384 * 1056 B ~= 17.3 MiB

    prep_kernel<<<64, 256, 0, stream>>>(a, mask, at_sw, flag);
    fused_kernel<<<B_ * NTILE_, 256, 0, stream>>>(h, at_sw, bvec, mask, flag, part);
    merge_kernel<<<B_, 256, 0, stream>>>(part, out);
}